// Round 13
// baseline (509.287 us; speedup 1.0000x reference)
//
#include <hip/hip_runtime.h>
#include <hip/hip_bf16.h>
#include <hip/hip_fp16.h>

#define N_NODES  50000
#define N_EDGES  800000
#define D        128
#define N_GRAPHS 64
#define CAP      64          // bucket capacity; in-deg ~ Poisson(16), P(>=64) ~ 1e-19
#define EW_SCALE 1048576.0f  // 2^20 fixed-point for packed weighted-degree
#define NB_GEMM1 391         // ceil(50000/128)
#define NB_FILL  3125        // 800000/256
#define NB_AGG   12500       // N_NODES/4

typedef _Float16 half8 __attribute__((ext_vector_type(8)));
typedef float   float4v __attribute__((ext_vector_type(4)));

__device__ __forceinline__ float2 h2f(unsigned int u) {
    __half2 h = *reinterpret_cast<__half2*>(&u);
    return __half22float2(h);
}
__device__ __forceinline__ unsigned int f2h(float a, float b) {
    __half2 h = __floats2half2_rn(a, b);
    return *reinterpret_cast<unsigned int*>(&h);
}
__device__ __forceinline__ float hu2f(unsigned short u) {
    __half_raw hr; hr.x = u;
    return __half2float(__half(hr));
}

// ---------------------------------------------------------------------------
// FUSED: blocks [0,391) = gemm1 (fp32 x @ W1 -> fp16, BK=32, LDS=32KB);
//        blocks [391,3516) = fill (1 edge/thread, returning 64-bit atomic
//        on 50K spread counters). Bucket entry 4B: src:u16 | ew:fp16.
// ---------------------------------------------------------------------------
__global__ __launch_bounds__(256) void fused_gemm1_fill(const float* __restrict__ X,
                                                        const float* __restrict__ W,
                                                        __half* __restrict__ Yh,
                                                        const int* __restrict__ ei,
                                                        const float* __restrict__ ew,
                                                        unsigned long long* __restrict__ packed,
                                                        unsigned int* __restrict__ bucket) {
    __shared__ float XT[32 * 128];  // 16 KB
    __shared__ float Ws[32 * 128];  // 16 KB

    if (blockIdx.x >= NB_GEMM1) {
        int e = (blockIdx.x - NB_GEMM1) * 256 + threadIdx.x;
        if (e >= N_EDGES) return;
        int r = ei[e];
        int c = ei[N_EDGES + e];
        float w = ew[e];
        unsigned long long add = (1ULL << 40) | (unsigned long long)(unsigned)(w * EW_SCALE + 0.5f);
        unsigned long long old = atomicAdd(&packed[c], add);
        unsigned pos = (unsigned)(old >> 40);
        if (pos < CAP) {
            unsigned short wh = __half_as_ushort(__float2half_rn(w));
            bucket[(size_t)c * CAP + pos] = (unsigned)r | ((unsigned)wh << 16);
        }
        return;
    }

    const int tid  = threadIdx.x;
    const int row0 = blockIdx.x * 128;
    const int tr = tid >> 4, tc = tid & 15;
    float acc[8][8] = {};

    for (int kt = 0; kt < 4; kt++) {
        const int kbase = kt * 32;
        {
            const float4* src = (const float4*)(W + kbase * 128);
            float4* dst = (float4*)Ws;
            for (int i = tid; i < 1024; i += 256) dst[i] = src[i];
        }
        {
            int r  = tid >> 1;
            int rr = row0 + r; if (rr >= N_NODES) rr = N_NODES - 1;
            int k0 = (tid & 1) * 16;
            const float4* src = (const float4*)(X + (size_t)rr * 128 + kbase + k0);
#pragma unroll
            for (int i = 0; i < 4; i++) {
                float4 v = src[i];
                int k = k0 + i * 4;
                XT[(k + 0) * 128 + r] = v.x;
                XT[(k + 1) * 128 + r] = v.y;
                XT[(k + 2) * 128 + r] = v.z;
                XT[(k + 3) * 128 + r] = v.w;
            }
        }
        __syncthreads();
#pragma unroll 4
        for (int k = 0; k < 32; k++) {
            float xs[8], ws[8];
            *(float4*)&xs[0] = *(const float4*)(XT + k * 128 + tr * 8);
            *(float4*)&xs[4] = *(const float4*)(XT + k * 128 + tr * 8 + 4);
            *(float4*)&ws[0] = *(const float4*)(Ws + k * 128 + tc * 8);
            *(float4*)&ws[4] = *(const float4*)(Ws + k * 128 + tc * 8 + 4);
#pragma unroll
            for (int i = 0; i < 8; i++)
#pragma unroll
                for (int j = 0; j < 8; j++)
                    acc[i][j] += xs[i] * ws[j];
        }
        __syncthreads();
    }
#pragma unroll
    for (int i = 0; i < 8; i++) {
        int r = row0 + tr * 8 + i;
        if (r < N_NODES) {
            uint4 p;
            p.x = f2h(acc[i][0], acc[i][1]);
            p.y = f2h(acc[i][2], acc[i][3]);
            p.z = f2h(acc[i][4], acc[i][5]);
            p.w = f2h(acc[i][6], acc[i][7]);
            *(uint4*)(Yh + (size_t)r * 128 + tc * 8) = p;
        }
    }
}

// ---------------------------------------------------------------------------
// MERGED unpack + prescale (12500 blocks, 4 nodes/block):
// threads 0..3 unpack packed -> cnt/dinv/gstart; all 256 threads then do the
// coalesced in-place x' = dinv * x scale (256 half2 = 4 nodes exactly).
// ---------------------------------------------------------------------------
__global__ __launch_bounds__(256) void dinv_scale_kernel(const unsigned long long* __restrict__ packed,
                                                         int* __restrict__ cnt, float* __restrict__ dinv,
                                                         const int* __restrict__ batch,
                                                         int* __restrict__ gstart,
                                                         unsigned int* __restrict__ xh) {
    __shared__ float sdv[4];
    const int node0 = blockIdx.x * 4;
    const int t = threadIdx.x;
    if (t < 4) {
        int node = node0 + t;
        unsigned long long p = packed[node];
        int c = (int)(p >> 40);
        cnt[node] = c < CAP ? c : CAP;
        float dv = rsqrtf(1.0f + (float)(p & 0xFFFFFFFFFFULL) * (1.0f / EW_SCALE));
        dinv[node] = dv;
        sdv[t] = dv;
        int a = batch[node];
        int pg = (node == 0) ? -1 : batch[node - 1];
        for (int g = pg + 1; g <= a; g++) gstart[g] = node;
        if (node == N_NODES - 1)
            for (int g = a + 1; g <= N_GRAPHS; g++) gstart[g] = N_NODES;
    }
    __syncthreads();
    float dv = sdv[t >> 6];
    size_t idx = (size_t)node0 * 64 + t;
    float2 f = h2f(xh[idx]);
    xh[idx] = f2h(f.x * dv, f.y * dv);
}

// ---------------------------------------------------------------------------
// gemm2 via MFMA fp16: Y = X(fp16) @ W(fp32->fp16 in-reg), epilogue *dinv.
// ---------------------------------------------------------------------------
__global__ __launch_bounds__(256) void gemm2_mfma(const __half* __restrict__ Xh,
                                                  const float* __restrict__ W,
                                                  const float* __restrict__ dinv,
                                                  __half* __restrict__ Yh) {
    const int wv   = threadIdx.x >> 6;
    const int lane = threadIdx.x & 63;
    const int quad = lane >> 4;
    const int l16  = lane & 15;
    const int row0 = blockIdx.x * 64 + wv * 16;
    if (row0 >= N_NODES) return;

    float4v acc[8] = {};

#pragma unroll
    for (int kc = 0; kc < 4; kc++) {
        const int k0 = kc * 32;
        half8 a = *(const half8*)(Xh + (size_t)(row0 + l16) * 128 + k0 + quad * 8);
#pragma unroll
        for (int ct = 0; ct < 8; ct++) {
            const float* wp = W + (size_t)(k0 + quad * 8) * 128 + ct * 16 + l16;
            half8 b;
#pragma unroll
            for (int j = 0; j < 8; j++) b[j] = (_Float16)wp[j * 128];
            acc[ct] = __builtin_amdgcn_mfma_f32_16x16x32_f16(a, b, acc[ct], 0, 0, 0);
        }
    }

#pragma unroll
    for (int r = 0; r < 4; r++) {
        int row = row0 + quad * 4 + r;
        float s = dinv[row];
#pragma unroll
        for (int ct = 0; ct < 8; ct++) {
            Yh[(size_t)row * 128 + ct * 16 + l16] = __float2half_rn(acc[ct][r] * s);
        }
    }
}

// ---------------------------------------------------------------------------
// Layer-1 aggregation on pre-scaled x' (fp16 in/out):
//   out[c] = relu( dinv[c]*(x'[c] + sum ew_i * x'[src_i]) + b )
// ---------------------------------------------------------------------------
__global__ __launch_bounds__(256) void agg_bucket_kernel(const __half* __restrict__ xwh,
                                                         const int* __restrict__ cnt,
                                                         const unsigned int* __restrict__ bucket,
                                                         const float* __restrict__ dinv,
                                                         const float* __restrict__ bias,
                                                         __half* __restrict__ outh) {
    int node = blockIdx.x * 4 + (threadIdx.x >> 6);
    int lane = threadIdx.x & 63;
    const unsigned int* xh = (const unsigned int*)xwh;

    float dv = dinv[node];
    int n = cnt[node];

    unsigned int ehdr = (lane < n) ? bucket[(size_t)node * CAP + lane] : 0u;
    int eh = (int)ehdr;

    float2 xs = h2f(xh[(size_t)node * 64 + lane]);
    float accx = xs.x;
    float accy = xs.y;

    int i = 0;
    for (; i + 3 < n; i += 4) {
        unsigned v0u = (unsigned)__shfl(eh, i);
        unsigned v1u = (unsigned)__shfl(eh, i + 1);
        unsigned v2u = (unsigned)__shfl(eh, i + 2);
        unsigned v3u = (unsigned)__shfl(eh, i + 3);
        int r0 = v0u & 0xFFFF, r1 = v1u & 0xFFFF, r2 = v2u & 0xFFFF, r3 = v3u & 0xFFFF;
        float v0 = hu2f((unsigned short)(v0u >> 16));
        float v1 = hu2f((unsigned short)(v1u >> 16));
        float v2 = hu2f((unsigned short)(v2u >> 16));
        float v3 = hu2f((unsigned short)(v3u >> 16));
        float2 f0 = h2f(xh[(size_t)r0 * 64 + lane]);
        float2 f1 = h2f(xh[(size_t)r1 * 64 + lane]);
        float2 f2 = h2f(xh[(size_t)r2 * 64 + lane]);
        float2 f3 = h2f(xh[(size_t)r3 * 64 + lane]);
        accx += v0 * f0.x + v1 * f1.x + v2 * f2.x + v3 * f3.x;
        accy += v0 * f0.y + v1 * f1.y + v2 * f2.y + v3 * f3.y;
    }
    for (; i < n; i++) {
        unsigned v0u = (unsigned)__shfl(eh, i);
        int r0 = v0u & 0xFFFF;
        float v0 = hu2f((unsigned short)(v0u >> 16));
        float2 f0 = h2f(xh[(size_t)r0 * 64 + lane]);
        accx += v0 * f0.x;
        accy += v0 * f0.y;
    }

    float2 b = ((const float2*)bias)[lane];
    float ox = fmaxf(dv * accx + b.x, 0.0f);
    float oy = fmaxf(dv * accy + b.y, 0.0f);
    ((unsigned int*)outh)[(size_t)node * 64 + lane] = f2h(ox, oy);
}

// ---------------------------------------------------------------------------
// Layer-2 aggregation FUSED with head dot AND final reduction:
//   per node: s = relu(h2) . Wh  ->  LDS run-length combine (4 nodes/block)
//   -> 1-2 fire-and-forget atomics onto line-padded pooled[g*16]
//   -> last-block-done computes out[g] = pooled/cnt + bh.
// ---------------------------------------------------------------------------
__global__ __launch_bounds__(256) void agg_head_kernel(const __half* __restrict__ xwh,
                                                       const int* __restrict__ cnt,
                                                       const unsigned int* __restrict__ bucket,
                                                       const float* __restrict__ dinv,
                                                       const float* __restrict__ bias,
                                                       const float* __restrict__ Wh,
                                                       const int* __restrict__ batch,
                                                       const int* __restrict__ gstart,
                                                       const float* __restrict__ bh,
                                                       float* __restrict__ pooled,
                                                       unsigned int* __restrict__ done,
                                                       float* __restrict__ out) {
    int node = blockIdx.x * 4 + (threadIdx.x >> 6);
    int lane = threadIdx.x & 63;
    const unsigned int* xh = (const unsigned int*)xwh;

    float dv = dinv[node];
    int n = cnt[node];

    unsigned int ehdr = (lane < n) ? bucket[(size_t)node * CAP + lane] : 0u;
    int eh = (int)ehdr;

    float2 xs = h2f(xh[(size_t)node * 64 + lane]);
    float accx = xs.x;
    float accy = xs.y;

    int i = 0;
    for (; i + 3 < n; i += 4) {
        unsigned v0u = (unsigned)__shfl(eh, i);
        unsigned v1u = (unsigned)__shfl(eh, i + 1);
        unsigned v2u = (unsigned)__shfl(eh, i + 2);
        unsigned v3u = (unsigned)__shfl(eh, i + 3);
        int r0 = v0u & 0xFFFF, r1 = v1u & 0xFFFF, r2 = v2u & 0xFFFF, r3 = v3u & 0xFFFF;
        float v0 = hu2f((unsigned short)(v0u >> 16));
        float v1 = hu2f((unsigned short)(v1u >> 16));
        float v2 = hu2f((unsigned short)(v2u >> 16));
        float v3 = hu2f((unsigned short)(v3u >> 16));
        float2 f0 = h2f(xh[(size_t)r0 * 64 + lane]);
        float2 f1 = h2f(xh[(size_t)r1 * 64 + lane]);
        float2 f2 = h2f(xh[(size_t)r2 * 64 + lane]);
        float2 f3 = h2f(xh[(size_t)r3 * 64 + lane]);
        accx += v0 * f0.x + v1 * f1.x + v2 * f2.x + v3 * f3.x;
        accy += v0 * f0.y + v1 * f1.y + v2 * f2.y + v3 * f3.y;
    }
    for (; i < n; i++) {
        unsigned v0u = (unsigned)__shfl(eh, i);
        int r0 = v0u & 0xFFFF;
        float v0 = hu2f((unsigned short)(v0u >> 16));
        float2 f0 = h2f(xh[(size_t)r0 * 64 + lane]);
        accx += v0 * f0.x;
        accy += v0 * f0.y;
    }

    float2 b = ((const float2*)bias)[lane];
    float hx = fmaxf(dv * accx + b.x, 0.0f);
    float hy = fmaxf(dv * accy + b.y, 0.0f);
    float2 w = ((const float2*)Wh)[lane];
    float s = hx * w.x + hy * w.y;
#pragma unroll
    for (int off = 32; off > 0; off >>= 1) s += __shfl_down(s, off, 64);

    __shared__ float sdot[4];
    __shared__ int   sg[4];
    __shared__ bool  lastFlag;
    if (lane == 0) { sdot[threadIdx.x >> 6] = s; sg[threadIdx.x >> 6] = batch[node]; }
    __syncthreads();
    if (threadIdx.x == 0) {
        float acc = sdot[0]; int cg = sg[0];
#pragma unroll
        for (int k = 1; k < 4; k++) {
            if (sg[k] == cg) acc += sdot[k];
            else { atomicAdd(&pooled[cg * 16], acc); cg = sg[k]; acc = sdot[k]; }
        }
        atomicAdd(&pooled[cg * 16], acc);
        __threadfence();
        unsigned p = atomicAdd(done, 1u);
        lastFlag = (p == (unsigned)(NB_AGG - 1));
    }
    __syncthreads();
    if (lastFlag && threadIdx.x < N_GRAPHS) {
        int g = threadIdx.x;
        float sv = atomicAdd(&pooled[g * 16], 0.0f);   // coherent RMW read
        int a = gstart[g], bb = gstart[g + 1];
        out[g] = sv / fmaxf((float)(bb - a), 1.0f) + bh[0];
    }
}

// ---------------------------------------------------------------------------
extern "C" void kernel_launch(void* const* d_in, const int* in_sizes, int n_in,
                              void* d_out, int out_size, void* d_ws, size_t ws_size,
                              hipStream_t stream) {
    const float* x   = (const float*)d_in[0];
    const float* ew  = (const float*)d_in[1];
    const float* W1  = (const float*)d_in[2];
    const float* b1  = (const float*)d_in[3];
    const float* W2  = (const float*)d_in[4];
    const float* b2  = (const float*)d_in[5];
    const float* Wh  = (const float*)d_in[6];
    const float* bh  = (const float*)d_in[7];
    const int*   ei  = (const int*)d_in[8];
    const int*   bat = (const int*)d_in[9];
    float* out = (float*)d_out;

    char* ws = (char*)d_ws;
    __half* bufAh  = (__half*)ws;                         ws += (size_t)N_NODES * D * 2;
    __half* bufBh  = (__half*)ws;                         ws += (size_t)N_NODES * D * 2;
    unsigned int* bucket = (unsigned int*)ws;             ws += (size_t)N_NODES * CAP * 4;
    // contiguous zero-region: packed | pooled(64x16 f32, line-padded) | done
    unsigned long long* packed = (unsigned long long*)ws; ws += (size_t)N_NODES * 8;
    float*  pooled = (float*)ws;                          ws += (size_t)N_GRAPHS * 16 * 4;
    unsigned int* done = (unsigned int*)ws;               ws += 16;
    float*  dinv   = (float*)ws;                          ws += (size_t)N_NODES * 4;
    int*    cnt    = (int*)ws;                            ws += (size_t)N_NODES * 4;
    int*    gstart = (int*)ws;                            ws += (N_GRAPHS + 1) * 4;

    const size_t zero_bytes = (size_t)N_NODES * 8 + (size_t)N_GRAPHS * 16 * 4 + 16;
    const int nb_gemm2 = (N_NODES + 63) / 64;         // 782

    hipMemsetAsync(packed, 0, zero_bytes, stream);

    // gemm1 (x@W1 -> fp16) overlapped with fill (atomic-floor-bound)
    fused_gemm1_fill<<<NB_GEMM1 + NB_FILL, 256, 0, stream>>>(x, W1, bufAh, ei, ew, packed, bucket);

    // unpack + prescale, fully parallel (12500 blocks, 4 nodes each)
    dinv_scale_kernel<<<NB_AGG, 256, 0, stream>>>(packed, cnt, dinv, bat, gstart,
                                                  (unsigned int*)bufAh);

    // layer 1
    agg_bucket_kernel<<<NB_AGG, 256, 0, stream>>>(bufAh, cnt, bucket, dinv, b1, bufBh);

    // layer 2 (MFMA gemm, dinv folded) + fused head dot + last-block final
    gemm2_mfma<<<nb_gemm2, 256, 0, stream>>>(bufBh, W2, dinv, bufAh);
    agg_head_kernel<<<NB_AGG, 256, 0, stream>>>(bufAh, cnt, bucket, dinv, b2, Wh,
                                                bat, gstart, bh, pooled, done, out);
}

// Round 14
// 232.074 us; speedup vs baseline: 2.1945x; 2.1945x over previous
//
#include <hip/hip_runtime.h>
#include <hip/hip_bf16.h>
#include <hip/hip_fp16.h>

#define N_NODES  50000
#define N_EDGES  800000
#define D        128
#define N_GRAPHS 64
#define CAP      64          // bucket capacity; in-deg ~ Poisson(16), P(>=64) ~ 1e-19
#define EW_SCALE 1048576.0f  // 2^20 fixed-point for packed weighted-degree
#define NB_GEMM1 391         // ceil(50000/128)
#define NB_FILL  3125        // 800000/256
#define NB_AGG   12500       // N_NODES/4

typedef _Float16 half8 __attribute__((ext_vector_type(8)));
typedef float   float4v __attribute__((ext_vector_type(4)));

__device__ __forceinline__ float2 h2f(unsigned int u) {
    __half2 h = *reinterpret_cast<__half2*>(&u);
    return __half22float2(h);
}
__device__ __forceinline__ unsigned int f2h(float a, float b) {
    __half2 h = __floats2half2_rn(a, b);
    return *reinterpret_cast<unsigned int*>(&h);
}
__device__ __forceinline__ float hu2f(unsigned short u) {
    __half_raw hr; hr.x = u;
    return __half2float(__half(hr));
}

// ---------------------------------------------------------------------------
// FUSED: blocks [0,391) = gemm1 (fp32 x @ W1 -> fp16, BK=32, LDS=32KB);
//        blocks [391,3516) = fill (1 edge/thread, returning 64-bit atomic
//        on 50K spread counters). Bucket entry 4B: src:u16 | ew:fp16.
// ---------------------------------------------------------------------------
__global__ __launch_bounds__(256) void fused_gemm1_fill(const float* __restrict__ X,
                                                        const float* __restrict__ W,
                                                        __half* __restrict__ Yh,
                                                        const int* __restrict__ ei,
                                                        const float* __restrict__ ew,
                                                        unsigned long long* __restrict__ packed,
                                                        unsigned int* __restrict__ bucket) {
    __shared__ float XT[32 * 128];  // 16 KB
    __shared__ float Ws[32 * 128];  // 16 KB

    if (blockIdx.x >= NB_GEMM1) {
        int e = (blockIdx.x - NB_GEMM1) * 256 + threadIdx.x;
        if (e >= N_EDGES) return;
        int r = ei[e];
        int c = ei[N_EDGES + e];
        float w = ew[e];
        unsigned long long add = (1ULL << 40) | (unsigned long long)(unsigned)(w * EW_SCALE + 0.5f);
        unsigned long long old = atomicAdd(&packed[c], add);
        unsigned pos = (unsigned)(old >> 40);
        if (pos < CAP) {
            unsigned short wh = __half_as_ushort(__float2half_rn(w));
            bucket[(size_t)c * CAP + pos] = (unsigned)r | ((unsigned)wh << 16);
        }
        return;
    }

    const int tid  = threadIdx.x;
    const int row0 = blockIdx.x * 128;
    const int tr = tid >> 4, tc = tid & 15;
    float acc[8][8] = {};

    for (int kt = 0; kt < 4; kt++) {
        const int kbase = kt * 32;
        {
            const float4* src = (const float4*)(W + kbase * 128);
            float4* dst = (float4*)Ws;
            for (int i = tid; i < 1024; i += 256) dst[i] = src[i];
        }
        {
            int r  = tid >> 1;
            int rr = row0 + r; if (rr >= N_NODES) rr = N_NODES - 1;
            int k0 = (tid & 1) * 16;
            const float4* src = (const float4*)(X + (size_t)rr * 128 + kbase + k0);
#pragma unroll
            for (int i = 0; i < 4; i++) {
                float4 v = src[i];
                int k = k0 + i * 4;
                XT[(k + 0) * 128 + r] = v.x;
                XT[(k + 1) * 128 + r] = v.y;
                XT[(k + 2) * 128 + r] = v.z;
                XT[(k + 3) * 128 + r] = v.w;
            }
        }
        __syncthreads();
#pragma unroll 4
        for (int k = 0; k < 32; k++) {
            float xs[8], ws[8];
            *(float4*)&xs[0] = *(const float4*)(XT + k * 128 + tr * 8);
            *(float4*)&xs[4] = *(const float4*)(XT + k * 128 + tr * 8 + 4);
            *(float4*)&ws[0] = *(const float4*)(Ws + k * 128 + tc * 8);
            *(float4*)&ws[4] = *(const float4*)(Ws + k * 128 + tc * 8 + 4);
#pragma unroll
            for (int i = 0; i < 8; i++)
#pragma unroll
                for (int j = 0; j < 8; j++)
                    acc[i][j] += xs[i] * ws[j];
        }
        __syncthreads();
    }
#pragma unroll
    for (int i = 0; i < 8; i++) {
        int r = row0 + tr * 8 + i;
        if (r < N_NODES) {
            uint4 p;
            p.x = f2h(acc[i][0], acc[i][1]);
            p.y = f2h(acc[i][2], acc[i][3]);
            p.z = f2h(acc[i][4], acc[i][5]);
            p.w = f2h(acc[i][6], acc[i][7]);
            *(uint4*)(Yh + (size_t)r * 128 + tc * 8) = p;
        }
    }
}

// ---------------------------------------------------------------------------
// MERGED unpack + prescale (12500 blocks, 4 nodes/block):
// threads 0..3 unpack packed -> cnt/dinv/gstart; all 256 threads then do the
// coalesced in-place x' = dinv * x scale (256 half2 = 4 nodes exactly).
// ---------------------------------------------------------------------------
__global__ __launch_bounds__(256) void dinv_scale_kernel(const unsigned long long* __restrict__ packed,
                                                         int* __restrict__ cnt, float* __restrict__ dinv,
                                                         const int* __restrict__ batch,
                                                         int* __restrict__ gstart,
                                                         unsigned int* __restrict__ xh) {
    __shared__ float sdv[4];
    const int node0 = blockIdx.x * 4;
    const int t = threadIdx.x;
    if (t < 4) {
        int node = node0 + t;
        unsigned long long p = packed[node];
        int c = (int)(p >> 40);
        cnt[node] = c < CAP ? c : CAP;
        float dv = rsqrtf(1.0f + (float)(p & 0xFFFFFFFFFFULL) * (1.0f / EW_SCALE));
        dinv[node] = dv;
        sdv[t] = dv;
        int a = batch[node];
        int pg = (node == 0) ? -1 : batch[node - 1];
        for (int g = pg + 1; g <= a; g++) gstart[g] = node;
        if (node == N_NODES - 1)
            for (int g = a + 1; g <= N_GRAPHS; g++) gstart[g] = N_NODES;
    }
    __syncthreads();
    float dv = sdv[t >> 6];
    size_t idx = (size_t)node0 * 64 + t;
    float2 f = h2f(xh[idx]);
    xh[idx] = f2h(f.x * dv, f.y * dv);
}

// ---------------------------------------------------------------------------
// gemm2 via MFMA fp16: Y = X(fp16) @ W(fp32->fp16 in-reg), epilogue *dinv.
// ---------------------------------------------------------------------------
__global__ __launch_bounds__(256) void gemm2_mfma(const __half* __restrict__ Xh,
                                                  const float* __restrict__ W,
                                                  const float* __restrict__ dinv,
                                                  __half* __restrict__ Yh) {
    const int wv   = threadIdx.x >> 6;
    const int lane = threadIdx.x & 63;
    const int quad = lane >> 4;
    const int l16  = lane & 15;
    const int row0 = blockIdx.x * 64 + wv * 16;
    if (row0 >= N_NODES) return;

    float4v acc[8] = {};

#pragma unroll
    for (int kc = 0; kc < 4; kc++) {
        const int k0 = kc * 32;
        half8 a = *(const half8*)(Xh + (size_t)(row0 + l16) * 128 + k0 + quad * 8);
#pragma unroll
        for (int ct = 0; ct < 8; ct++) {
            const float* wp = W + (size_t)(k0 + quad * 8) * 128 + ct * 16 + l16;
            half8 b;
#pragma unroll
            for (int j = 0; j < 8; j++) b[j] = (_Float16)wp[j * 128];
            acc[ct] = __builtin_amdgcn_mfma_f32_16x16x32_f16(a, b, acc[ct], 0, 0, 0);
        }
    }

#pragma unroll
    for (int r = 0; r < 4; r++) {
        int row = row0 + quad * 4 + r;
        float s = dinv[row];
#pragma unroll
        for (int ct = 0; ct < 8; ct++) {
            Yh[(size_t)row * 128 + ct * 16 + l16] = __float2half_rn(acc[ct][r] * s);
        }
    }
}

// ---------------------------------------------------------------------------
// Layer-1 aggregation on pre-scaled x' (fp16 in/out):
//   out[c] = relu( dinv[c]*(x'[c] + sum ew_i * x'[src_i]) + b )
// ---------------------------------------------------------------------------
__global__ __launch_bounds__(256) void agg_bucket_kernel(const __half* __restrict__ xwh,
                                                         const int* __restrict__ cnt,
                                                         const unsigned int* __restrict__ bucket,
                                                         const float* __restrict__ dinv,
                                                         const float* __restrict__ bias,
                                                         __half* __restrict__ outh) {
    int node = blockIdx.x * 4 + (threadIdx.x >> 6);
    int lane = threadIdx.x & 63;
    const unsigned int* xh = (const unsigned int*)xwh;

    float dv = dinv[node];
    int n = cnt[node];

    unsigned int ehdr = (lane < n) ? bucket[(size_t)node * CAP + lane] : 0u;
    int eh = (int)ehdr;

    float2 xs = h2f(xh[(size_t)node * 64 + lane]);
    float accx = xs.x;
    float accy = xs.y;

    int i = 0;
    for (; i + 3 < n; i += 4) {
        unsigned v0u = (unsigned)__shfl(eh, i);
        unsigned v1u = (unsigned)__shfl(eh, i + 1);
        unsigned v2u = (unsigned)__shfl(eh, i + 2);
        unsigned v3u = (unsigned)__shfl(eh, i + 3);
        int r0 = v0u & 0xFFFF, r1 = v1u & 0xFFFF, r2 = v2u & 0xFFFF, r3 = v3u & 0xFFFF;
        float v0 = hu2f((unsigned short)(v0u >> 16));
        float v1 = hu2f((unsigned short)(v1u >> 16));
        float v2 = hu2f((unsigned short)(v2u >> 16));
        float v3 = hu2f((unsigned short)(v3u >> 16));
        float2 f0 = h2f(xh[(size_t)r0 * 64 + lane]);
        float2 f1 = h2f(xh[(size_t)r1 * 64 + lane]);
        float2 f2 = h2f(xh[(size_t)r2 * 64 + lane]);
        float2 f3 = h2f(xh[(size_t)r3 * 64 + lane]);
        accx += v0 * f0.x + v1 * f1.x + v2 * f2.x + v3 * f3.x;
        accy += v0 * f0.y + v1 * f1.y + v2 * f2.y + v3 * f3.y;
    }
    for (; i < n; i++) {
        unsigned v0u = (unsigned)__shfl(eh, i);
        int r0 = v0u & 0xFFFF;
        float v0 = hu2f((unsigned short)(v0u >> 16));
        float2 f0 = h2f(xh[(size_t)r0 * 64 + lane]);
        accx += v0 * f0.x;
        accy += v0 * f0.y;
    }

    float2 b = ((const float2*)bias)[lane];
    float ox = fmaxf(dv * accx + b.x, 0.0f);
    float oy = fmaxf(dv * accy + b.y, 0.0f);
    ((unsigned int*)outh)[(size_t)node * 64 + lane] = f2h(ox, oy);
}

// ---------------------------------------------------------------------------
// Layer-2 aggregation FUSED with head dot: nodedot[c] = relu(h2[c]) . Wh
// (plain store per node — NO fences/atomics; r13 showed grid-completion
// protocols inside a throughput kernel cost 8x).
// ---------------------------------------------------------------------------
__global__ __launch_bounds__(256) void agg_head_kernel(const __half* __restrict__ xwh,
                                                       const int* __restrict__ cnt,
                                                       const unsigned int* __restrict__ bucket,
                                                       const float* __restrict__ dinv,
                                                       const float* __restrict__ bias,
                                                       const float* __restrict__ Wh,
                                                       float* __restrict__ nodedot) {
    int node = blockIdx.x * 4 + (threadIdx.x >> 6);
    int lane = threadIdx.x & 63;
    const unsigned int* xh = (const unsigned int*)xwh;

    float dv = dinv[node];
    int n = cnt[node];

    unsigned int ehdr = (lane < n) ? bucket[(size_t)node * CAP + lane] : 0u;
    int eh = (int)ehdr;

    float2 xs = h2f(xh[(size_t)node * 64 + lane]);
    float accx = xs.x;
    float accy = xs.y;

    int i = 0;
    for (; i + 3 < n; i += 4) {
        unsigned v0u = (unsigned)__shfl(eh, i);
        unsigned v1u = (unsigned)__shfl(eh, i + 1);
        unsigned v2u = (unsigned)__shfl(eh, i + 2);
        unsigned v3u = (unsigned)__shfl(eh, i + 3);
        int r0 = v0u & 0xFFFF, r1 = v1u & 0xFFFF, r2 = v2u & 0xFFFF, r3 = v3u & 0xFFFF;
        float v0 = hu2f((unsigned short)(v0u >> 16));
        float v1 = hu2f((unsigned short)(v1u >> 16));
        float v2 = hu2f((unsigned short)(v2u >> 16));
        float v3 = hu2f((unsigned short)(v3u >> 16));
        float2 f0 = h2f(xh[(size_t)r0 * 64 + lane]);
        float2 f1 = h2f(xh[(size_t)r1 * 64 + lane]);
        float2 f2 = h2f(xh[(size_t)r2 * 64 + lane]);
        float2 f3 = h2f(xh[(size_t)r3 * 64 + lane]);
        accx += v0 * f0.x + v1 * f1.x + v2 * f2.x + v3 * f3.x;
        accy += v0 * f0.y + v1 * f1.y + v2 * f2.y + v3 * f3.y;
    }
    for (; i < n; i++) {
        unsigned v0u = (unsigned)__shfl(eh, i);
        int r0 = v0u & 0xFFFF;
        float v0 = hu2f((unsigned short)(v0u >> 16));
        float2 f0 = h2f(xh[(size_t)r0 * 64 + lane]);
        accx += v0 * f0.x;
        accy += v0 * f0.y;
    }

    float2 b = ((const float2*)bias)[lane];
    float hx = fmaxf(dv * accx + b.x, 0.0f);
    float hy = fmaxf(dv * accy + b.y, 0.0f);
    float2 w = ((const float2*)Wh)[lane];
    float s = hx * w.x + hy * w.y;
#pragma unroll
    for (int off = 32; off > 0; off >>= 1) s += __shfl_down(s, off, 64);
    if (lane == 0) nodedot[node] = s;
}

// out[g] = (sum nodedot over graph) / cnt + bh
__global__ __launch_bounds__(256) void final2_kernel(const float* __restrict__ nodedot,
                                                     const int* __restrict__ gstart,
                                                     const float* __restrict__ bh,
                                                     float* __restrict__ out) {
    __shared__ float red[256];
    int g = blockIdx.x;
    int a = gstart[g], b = gstart[g + 1];
    float s = 0.0f;
    for (int n = a + threadIdx.x; n < b; n += 256) s += nodedot[n];
    red[threadIdx.x] = s;
    __syncthreads();
#pragma unroll
    for (int off = 128; off > 0; off >>= 1) {
        if (threadIdx.x < off) red[threadIdx.x] += red[threadIdx.x + off];
        __syncthreads();
    }
    if (threadIdx.x == 0)
        out[g] = red[0] / fmaxf((float)(b - a), 1.0f) + bh[0];
}

// ---------------------------------------------------------------------------
extern "C" void kernel_launch(void* const* d_in, const int* in_sizes, int n_in,
                              void* d_out, int out_size, void* d_ws, size_t ws_size,
                              hipStream_t stream) {
    const float* x   = (const float*)d_in[0];
    const float* ew  = (const float*)d_in[1];
    const float* W1  = (const float*)d_in[2];
    const float* b1  = (const float*)d_in[3];
    const float* W2  = (const float*)d_in[4];
    const float* b2  = (const float*)d_in[5];
    const float* Wh  = (const float*)d_in[6];
    const float* bh  = (const float*)d_in[7];
    const int*   ei  = (const int*)d_in[8];
    const int*   bat = (const int*)d_in[9];
    float* out = (float*)d_out;

    char* ws = (char*)d_ws;
    __half* bufAh  = (__half*)ws;                         ws += (size_t)N_NODES * D * 2;
    __half* bufBh  = (__half*)ws;                         ws += (size_t)N_NODES * D * 2;
    unsigned int* bucket = (unsigned int*)ws;             ws += (size_t)N_NODES * CAP * 4;
    unsigned long long* packed = (unsigned long long*)ws; ws += (size_t)N_NODES * 8;
    float*  dinv    = (float*)ws;                         ws += (size_t)N_NODES * 4;
    int*    cnt     = (int*)ws;                           ws += (size_t)N_NODES * 4;
    int*    gstart  = (int*)ws;                           ws += (N_GRAPHS + 1) * 4;
    float*  nodedot = (float*)ws;                         ws += (size_t)N_NODES * 4;

    const int nb_gemm2 = (N_NODES + 63) / 64;         // 782

    hipMemsetAsync(packed, 0, (size_t)N_NODES * 8, stream);

    // gemm1 (x@W1 -> fp16) overlapped with fill (atomic-floor-bound)
    fused_gemm1_fill<<<NB_GEMM1 + NB_FILL, 256, 0, stream>>>(x, W1, bufAh, ei, ew, packed, bucket);

    // merged unpack + prescale, fully parallel (12500 blocks, 4 nodes each)
    dinv_scale_kernel<<<NB_AGG, 256, 0, stream>>>(packed, cnt, dinv, bat, gstart,
                                                  (unsigned int*)bufAh);

    // layer 1
    agg_bucket_kernel<<<NB_AGG, 256, 0, stream>>>(bufAh, cnt, bucket, dinv, b1, bufBh);

    // layer 2 (MFMA gemm, dinv folded) + fused head dot
    gemm2_mfma<<<nb_gemm2, 256, 0, stream>>>(bufBh, W2, dinv, bufAh);
    agg_head_kernel<<<NB_AGG, 256, 0, stream>>>(bufAh, cnt, bucket, dinv, b2, Wh, nodedot);

    // segment-sum + head bias
    final2_kernel<<<N_GRAPHS, 256, 0, stream>>>(nodedot, gstart, bh, out);
}

// Round 15
// 230.676 us; speedup vs baseline: 2.2078x; 1.0061x over previous
//
#include <hip/hip_runtime.h>
#include <hip/hip_bf16.h>
#include <hip/hip_fp16.h>

#define N_NODES  50000
#define N_EDGES  800000
#define D        128
#define N_GRAPHS 64
#define CAP      64          // bucket capacity; in-deg ~ Poisson(16), P(>=64) ~ 1e-19
#define EW_SCALE 1048576.0f  // 2^20 fixed-point for packed weighted-degree
#define NB_GEMM1 391         // ceil(50000/128)
#define NB_FILL  3125        // 800000/256
#define NB_AGG16 3125        // N_NODES/16

typedef _Float16 half8 __attribute__((ext_vector_type(8)));
typedef float   float4v __attribute__((ext_vector_type(4)));

__device__ __forceinline__ float2 h2f(unsigned int u) {
    __half2 h = *reinterpret_cast<__half2*>(&u);
    return __half22float2(h);
}
__device__ __forceinline__ unsigned int f2h(float a, float b) {
    __half2 h = __floats2half2_rn(a, b);
    return *reinterpret_cast<unsigned int*>(&h);
}
__device__ __forceinline__ float hu2f(unsigned short u) {
    __half_raw hr; hr.x = u;
    return __half2float(__half(hr));
}

// ---------------------------------------------------------------------------
// FUSED: blocks [0,391) = gemm1 (fp32 x @ W1 -> fp16 unscaled, BK=32);
//        blocks [391,3516) = fill (1 edge/thread, returning 64-bit atomic
//        on 50K spread counters). Bucket entry 4B: src:u16 | ew:fp16.
// ---------------------------------------------------------------------------
__global__ __launch_bounds__(256) void fused_gemm1_fill(const float* __restrict__ X,
                                                        const float* __restrict__ W,
                                                        __half* __restrict__ Yh,
                                                        const int* __restrict__ ei,
                                                        const float* __restrict__ ew,
                                                        unsigned long long* __restrict__ packed,
                                                        unsigned int* __restrict__ bucket) {
    __shared__ float XT[32 * 128];  // 16 KB
    __shared__ float Ws[32 * 128];  // 16 KB

    if (blockIdx.x >= NB_GEMM1) {
        int e = (blockIdx.x - NB_GEMM1) * 256 + threadIdx.x;
        if (e >= N_EDGES) return;
        int r = ei[e];
        int c = ei[N_EDGES + e];
        float w = ew[e];
        unsigned long long add = (1ULL << 40) | (unsigned long long)(unsigned)(w * EW_SCALE + 0.5f);
        unsigned long long old = atomicAdd(&packed[c], add);
        unsigned pos = (unsigned)(old >> 40);
        if (pos < CAP) {
            unsigned short wh = __half_as_ushort(__float2half_rn(w));
            bucket[(size_t)c * CAP + pos] = (unsigned)r | ((unsigned)wh << 16);
        }
        return;
    }

    const int tid  = threadIdx.x;
    const int row0 = blockIdx.x * 128;
    const int tr = tid >> 4, tc = tid & 15;
    float acc[8][8] = {};

    for (int kt = 0; kt < 4; kt++) {
        const int kbase = kt * 32;
        {
            const float4* src = (const float4*)(W + kbase * 128);
            float4* dst = (float4*)Ws;
            for (int i = tid; i < 1024; i += 256) dst[i] = src[i];
        }
        {
            int r  = tid >> 1;
            int rr = row0 + r; if (rr >= N_NODES) rr = N_NODES - 1;
            int k0 = (tid & 1) * 16;
            const float4* src = (const float4*)(X + (size_t)rr * 128 + kbase + k0);
#pragma unroll
            for (int i = 0; i < 4; i++) {
                float4 v = src[i];
                int k = k0 + i * 4;
                XT[(k + 0) * 128 + r] = v.x;
                XT[(k + 1) * 128 + r] = v.y;
                XT[(k + 2) * 128 + r] = v.z;
                XT[(k + 3) * 128 + r] = v.w;
            }
        }
        __syncthreads();
#pragma unroll 4
        for (int k = 0; k < 32; k++) {
            float xs[8], ws[8];
            *(float4*)&xs[0] = *(const float4*)(XT + k * 128 + tr * 8);
            *(float4*)&xs[4] = *(const float4*)(XT + k * 128 + tr * 8 + 4);
            *(float4*)&ws[0] = *(const float4*)(Ws + k * 128 + tc * 8);
            *(float4*)&ws[4] = *(const float4*)(Ws + k * 128 + tc * 8 + 4);
#pragma unroll
            for (int i = 0; i < 8; i++)
#pragma unroll
                for (int j = 0; j < 8; j++)
                    acc[i][j] += xs[i] * ws[j];
        }
        __syncthreads();
    }
#pragma unroll
    for (int i = 0; i < 8; i++) {
        int r = row0 + tr * 8 + i;
        if (r < N_NODES) {
            uint4 p;
            p.x = f2h(acc[i][0], acc[i][1]);
            p.y = f2h(acc[i][2], acc[i][3]);
            p.z = f2h(acc[i][4], acc[i][5]);
            p.w = f2h(acc[i][6], acc[i][7]);
            *(uint4*)(Yh + (size_t)r * 128 + tc * 8) = p;
        }
    }
}

// ---------------------------------------------------------------------------
// unpack cnt/dinv + graph starts (tiny; no feature prescale anymore)
// ---------------------------------------------------------------------------
__global__ void dinv_gstart_kernel(const unsigned long long* __restrict__ packed,
                                   int* __restrict__ cnt, float* __restrict__ dinv,
                                   const int* __restrict__ batch, int* __restrict__ gstart) {
    int i = blockIdx.x * 256 + threadIdx.x;
    if (i >= N_NODES) return;
    unsigned long long p = packed[i];
    int c = (int)(p >> 40);
    cnt[i] = c < CAP ? c : CAP;
    float deg = 1.0f + (float)(p & 0xFFFFFFFFFFULL) * (1.0f / EW_SCALE);
    dinv[i] = rsqrtf(deg);

    int a = batch[i];
    if (i == 0) {
        for (int g = 0; g <= a; g++) gstart[g] = 0;
    } else {
        int pg = batch[i - 1];
        for (int g = pg + 1; g <= a; g++) gstart[g] = i;
    }
    if (i == N_NODES - 1) {
        for (int g = a + 1; g <= N_GRAPHS; g++) gstart[g] = N_NODES;
    }
}

// ---------------------------------------------------------------------------
// Layer-1 aggregation + ROW-LOCAL gemm2 fusion. 16 nodes/block (4 waves x 4
// nodes serially). Gather phase on UNSCALED xw1 with val = ew*dinv[src]
// (dinv table is 200KB, L2-hot); h1 = relu(dv*(dv*x + sum val*x[src]) + b1)
// staged in LDS (16x136 fp16, padded); then each wave computes 2 col-tiles of
// x2' = dinv * (h1 @ W2) via MFMA and writes directly. No h1 round-trip.
// ---------------------------------------------------------------------------
__global__ __launch_bounds__(256) void agg1_gemm2_kernel(const __half* __restrict__ xw1,
                                                         const int* __restrict__ cnt,
                                                         const unsigned int* __restrict__ bucket,
                                                         const float* __restrict__ dinv,
                                                         const float* __restrict__ b1,
                                                         const float* __restrict__ W2,
                                                         __half* __restrict__ x2) {
    __shared__ _Float16 sh1[16][136];
    const int wv   = threadIdx.x >> 6;
    const int lane = threadIdx.x & 63;
    const unsigned int* xh = (const unsigned int*)xw1;
    const int node0 = blockIdx.x * 16;

    float2 bb = ((const float2*)b1)[lane];

#pragma unroll
    for (int j = 0; j < 4; j++) {
        int node = node0 + wv * 4 + j;
        float dv = dinv[node];
        int n = cnt[node];

        unsigned pk = 0u;
        if (lane < n) {
            unsigned eh = bucket[(size_t)node * CAP + lane];
            float v = hu2f((unsigned short)(eh >> 16)) * dinv[eh & 0xFFFFu];
            pk = (eh & 0xFFFFu) | ((unsigned)__half_as_ushort(__float2half_rn(v)) << 16);
        }
        int pki = (int)pk;

        float2 xs = h2f(xh[(size_t)node * 64 + lane]);
        float accx = dv * xs.x;
        float accy = dv * xs.y;

        int i = 0;
        for (; i + 3 < n; i += 4) {
            unsigned v0u = (unsigned)__shfl(pki, i);
            unsigned v1u = (unsigned)__shfl(pki, i + 1);
            unsigned v2u = (unsigned)__shfl(pki, i + 2);
            unsigned v3u = (unsigned)__shfl(pki, i + 3);
            int r0 = v0u & 0xFFFF, r1 = v1u & 0xFFFF, r2 = v2u & 0xFFFF, r3 = v3u & 0xFFFF;
            float v0 = hu2f((unsigned short)(v0u >> 16));
            float v1 = hu2f((unsigned short)(v1u >> 16));
            float v2 = hu2f((unsigned short)(v2u >> 16));
            float v3 = hu2f((unsigned short)(v3u >> 16));
            float2 f0 = h2f(xh[(size_t)r0 * 64 + lane]);
            float2 f1 = h2f(xh[(size_t)r1 * 64 + lane]);
            float2 f2 = h2f(xh[(size_t)r2 * 64 + lane]);
            float2 f3 = h2f(xh[(size_t)r3 * 64 + lane]);
            accx += v0 * f0.x + v1 * f1.x + v2 * f2.x + v3 * f3.x;
            accy += v0 * f0.y + v1 * f1.y + v2 * f2.y + v3 * f3.y;
        }
        for (; i < n; i++) {
            unsigned v0u = (unsigned)__shfl(pki, i);
            int r0 = v0u & 0xFFFF;
            float v0 = hu2f((unsigned short)(v0u >> 16));
            float2 f0 = h2f(xh[(size_t)r0 * 64 + lane]);
            accx += v0 * f0.x;
            accy += v0 * f0.y;
        }

        float hx = fmaxf(dv * accx + bb.x, 0.0f);
        float hy = fmaxf(dv * accy + bb.y, 0.0f);
        int lr = wv * 4 + j;
        sh1[lr][lane * 2]     = (_Float16)hx;
        sh1[lr][lane * 2 + 1] = (_Float16)hy;
    }
    __syncthreads();

    // --- MFMA: x2' rows node0..node0+15; wave wv does col-tiles wv*2, wv*2+1.
    const int quad = lane >> 4;
    const int l16  = lane & 15;
    float4v acc0 = {}, acc1 = {};
#pragma unroll
    for (int kc = 0; kc < 4; kc++) {
        const int k0 = kc * 32;
        half8 a = *(const half8*)(&sh1[l16][k0 + quad * 8]);
        {
            const float* wp = W2 + (size_t)(k0 + quad * 8) * 128 + (wv * 2) * 16 + l16;
            half8 b;
#pragma unroll
            for (int jj = 0; jj < 8; jj++) b[jj] = (_Float16)wp[jj * 128];
            acc0 = __builtin_amdgcn_mfma_f32_16x16x32_f16(a, b, acc0, 0, 0, 0);
        }
        {
            const float* wp = W2 + (size_t)(k0 + quad * 8) * 128 + (wv * 2 + 1) * 16 + l16;
            half8 b;
#pragma unroll
            for (int jj = 0; jj < 8; jj++) b[jj] = (_Float16)wp[jj * 128];
            acc1 = __builtin_amdgcn_mfma_f32_16x16x32_f16(a, b, acc1, 0, 0, 0);
        }
    }
#pragma unroll
    for (int r = 0; r < 4; r++) {
        int row = node0 + quad * 4 + r;
        float s = dinv[row];
        x2[(size_t)row * 128 + (wv * 2) * 16 + l16]     = __float2half_rn(acc0[r] * s);
        x2[(size_t)row * 128 + (wv * 2 + 1) * 16 + l16] = __float2half_rn(acc1[r] * s);
    }
}

// ---------------------------------------------------------------------------
// Layer-2 aggregation FUSED with head dot: nodedot[c] = relu(h2[c]) . Wh
// x2' carries dinv factors; bucket vals are raw ew. Plain store, no fences.
// ---------------------------------------------------------------------------
__global__ __launch_bounds__(256) void agg_head_kernel(const __half* __restrict__ xwh,
                                                       const int* __restrict__ cnt,
                                                       const unsigned int* __restrict__ bucket,
                                                       const float* __restrict__ dinv,
                                                       const float* __restrict__ bias,
                                                       const float* __restrict__ Wh,
                                                       float* __restrict__ nodedot) {
    int node = blockIdx.x * 4 + (threadIdx.x >> 6);
    int lane = threadIdx.x & 63;
    const unsigned int* xh = (const unsigned int*)xwh;

    float dv = dinv[node];
    int n = cnt[node];

    unsigned int ehdr = (lane < n) ? bucket[(size_t)node * CAP + lane] : 0u;
    int eh = (int)ehdr;

    float2 xs = h2f(xh[(size_t)node * 64 + lane]);
    float accx = xs.x;
    float accy = xs.y;

    int i = 0;
    for (; i + 3 < n; i += 4) {
        unsigned v0u = (unsigned)__shfl(eh, i);
        unsigned v1u = (unsigned)__shfl(eh, i + 1);
        unsigned v2u = (unsigned)__shfl(eh, i + 2);
        unsigned v3u = (unsigned)__shfl(eh, i + 3);
        int r0 = v0u & 0xFFFF, r1 = v1u & 0xFFFF, r2 = v2u & 0xFFFF, r3 = v3u & 0xFFFF;
        float v0 = hu2f((unsigned short)(v0u >> 16));
        float v1 = hu2f((unsigned short)(v1u >> 16));
        float v2 = hu2f((unsigned short)(v2u >> 16));
        float v3 = hu2f((unsigned short)(v3u >> 16));
        float2 f0 = h2f(xh[(size_t)r0 * 64 + lane]);
        float2 f1 = h2f(xh[(size_t)r1 * 64 + lane]);
        float2 f2 = h2f(xh[(size_t)r2 * 64 + lane]);
        float2 f3 = h2f(xh[(size_t)r3 * 64 + lane]);
        accx += v0 * f0.x + v1 * f1.x + v2 * f2.x + v3 * f3.x;
        accy += v0 * f0.y + v1 * f1.y + v2 * f2.y + v3 * f3.y;
    }
    for (; i < n; i++) {
        unsigned v0u = (unsigned)__shfl(eh, i);
        int r0 = v0u & 0xFFFF;
        float v0 = hu2f((unsigned short)(v0u >> 16));
        float2 f0 = h2f(xh[(size_t)r0 * 64 + lane]);
        accx += v0 * f0.x;
        accy += v0 * f0.y;
    }

    float2 b = ((const float2*)bias)[lane];
    float hx = fmaxf(dv * accx + b.x, 0.0f);
    float hy = fmaxf(dv * accy + b.y, 0.0f);
    float2 w = ((const float2*)Wh)[lane];
    float s = hx * w.x + hy * w.y;
#pragma unroll
    for (int off = 32; off > 0; off >>= 1) s += __shfl_down(s, off, 64);
    if (lane == 0) nodedot[node] = s;
}

// out[g] = (sum nodedot over graph) / cnt + bh
__global__ __launch_bounds__(256) void final2_kernel(const float* __restrict__ nodedot,
                                                     const int* __restrict__ gstart,
                                                     const float* __restrict__ bh,
                                                     float* __restrict__ out) {
    __shared__ float red[256];
    int g = blockIdx.x;
    int a = gstart[g], b = gstart[g + 1];
    float s = 0.0f;
    for (int n = a + threadIdx.x; n < b; n += 256) s += nodedot[n];
    red[threadIdx.x] = s;
    __syncthreads();
#pragma unroll
    for (int off = 128; off > 0; off >>= 1) {
        if (threadIdx.x < off) red[threadIdx.x] += red[threadIdx.x + off];
        __syncthreads();
    }
    if (threadIdx.x == 0)
        out[g] = red[0] / fmaxf((float)(b - a), 1.0f) + bh[0];
}

// ---------------------------------------------------------------------------
extern "C" void kernel_launch(void* const* d_in, const int* in_sizes, int n_in,
                              void* d_out, int out_size, void* d_ws, size_t ws_size,
                              hipStream_t stream) {
    const float* x   = (const float*)d_in[0];
    const float* ew  = (const float*)d_in[1];
    const float* W1  = (const float*)d_in[2];
    const float* b1  = (const float*)d_in[3];
    const float* W2  = (const float*)d_in[4];
    const float* b2  = (const float*)d_in[5];
    const float* Wh  = (const float*)d_in[6];
    const float* bh  = (const float*)d_in[7];
    const int*   ei  = (const int*)d_in[8];
    const int*   bat = (const int*)d_in[9];
    float* out = (float*)d_out;

    char* ws = (char*)d_ws;
    __half* bufAh  = (__half*)ws;                         ws += (size_t)N_NODES * D * 2;
    __half* bufBh  = (__half*)ws;                         ws += (size_t)N_NODES * D * 2;
    unsigned int* bucket = (unsigned int*)ws;             ws += (size_t)N_NODES * CAP * 4;
    unsigned long long* packed = (unsigned long long*)ws; ws += (size_t)N_NODES * 8;
    float*  dinv    = (float*)ws;                         ws += (size_t)N_NODES * 4;
    int*    cnt     = (int*)ws;                           ws += (size_t)N_NODES * 4;
    int*    gstart  = (int*)ws;                           ws += (N_GRAPHS + 1) * 4;
    float*  nodedot = (float*)ws;                         ws += (size_t)N_NODES * 4;

    const int nb_nodes = (N_NODES + 255) / 256;       // 196
    const int nb_agg4  = N_NODES / 4;                 // 12500

    hipMemsetAsync(packed, 0, (size_t)N_NODES * 8, stream);

    // gemm1 (x@W1 -> fp16, unscaled) overlapped with fill (atomic-floor-bound)
    fused_gemm1_fill<<<NB_GEMM1 + NB_FILL, 256, 0, stream>>>(x, W1, bufAh, ei, ew, packed, bucket);

    // tiny unpack (no prescale — agg1 applies dinv[src] per edge)
    dinv_gstart_kernel<<<nb_nodes, 256, 0, stream>>>(packed, cnt, dinv, bat, gstart);

    // layer 1 agg + row-local gemm2 fusion -> x2' in bufBh
    agg1_gemm2_kernel<<<NB_AGG16, 256, 0, stream>>>(bufAh, cnt, bucket, dinv, b1, W2, bufBh);

    // layer 2 agg + head dot
    agg_head_kernel<<<nb_agg4, 256, 0, stream>>>(bufBh, cnt, bucket, dinv, b2, Wh, nodedot);

    // segment-sum + head bias
    final2_kernel<<<N_GRAPHS, 256, 0, stream>>>(nodedot, gstart, bh, out);
}

// Round 16
// 225.893 us; speedup vs baseline: 2.2545x; 1.0212x over previous
//
#include <hip/hip_runtime.h>
#include <hip/hip_bf16.h>
#include <hip/hip_fp16.h>

#define N_NODES  50000
#define N_EDGES  800000
#define D        128
#define N_GRAPHS 64
#define CAP      64          // bucket capacity; in-deg ~ Poisson(16), P(>=64) ~ 1e-19
#define EW_SCALE 1048576.0f  // 2^20 fixed-point for packed weighted-degree
#define NB_GEMM1 391         // ceil(50000/128)
#define NB_FILL  3125        // 800000/256
#define NB_AGG16 3125        // N_NODES/16

typedef _Float16 half8 __attribute__((ext_vector_type(8)));
typedef float   float4v __attribute__((ext_vector_type(4)));

__device__ __forceinline__ float2 h2f(unsigned int u) {
    __half2 h = *reinterpret_cast<__half2*>(&u);
    return __half22float2(h);
}
__device__ __forceinline__ unsigned int f2h(float a, float b) {
    __half2 h = __floats2half2_rn(a, b);
    return *reinterpret_cast<unsigned int*>(&h);
}
__device__ __forceinline__ float hu2f(unsigned short u) {
    __half_raw hr; hr.x = u;
    return __half2float(__half(hr));
}
// unpack packed word -> (cnt, dinv)
__device__ __forceinline__ void unpack_pd(unsigned long long p, int& n, float& dv) {
    int c = (int)(p >> 40);
    n = c < CAP ? c : CAP;
    dv = rsqrtf(1.0f + (float)(p & 0xFFFFFFFFFFULL) * (1.0f / EW_SCALE));
}

// ---------------------------------------------------------------------------
// FUSED: blocks [0,391) = gemm1 (fp32 x @ W1 -> fp16 unscaled, BK=32);
//        blocks [391,3516) = fill (1 edge/thread, returning 64-bit atomic
//        on 50K spread counters). Bucket entry 4B: src:u16 | ew:fp16.
// ---------------------------------------------------------------------------
__global__ __launch_bounds__(256) void fused_gemm1_fill(const float* __restrict__ X,
                                                        const float* __restrict__ W,
                                                        __half* __restrict__ Yh,
                                                        const int* __restrict__ ei,
                                                        const float* __restrict__ ew,
                                                        unsigned long long* __restrict__ packed,
                                                        unsigned int* __restrict__ bucket) {
    __shared__ float XT[32 * 128];  // 16 KB
    __shared__ float Ws[32 * 128];  // 16 KB

    if (blockIdx.x >= NB_GEMM1) {
        int e = (blockIdx.x - NB_GEMM1) * 256 + threadIdx.x;
        if (e >= N_EDGES) return;
        int r = ei[e];
        int c = ei[N_EDGES + e];
        float w = ew[e];
        unsigned long long add = (1ULL << 40) | (unsigned long long)(unsigned)(w * EW_SCALE + 0.5f);
        unsigned long long old = atomicAdd(&packed[c], add);
        unsigned pos = (unsigned)(old >> 40);
        if (pos < CAP) {
            unsigned short wh = __half_as_ushort(__float2half_rn(w));
            bucket[(size_t)c * CAP + pos] = (unsigned)r | ((unsigned)wh << 16);
        }
        return;
    }

    const int tid  = threadIdx.x;
    const int row0 = blockIdx.x * 128;
    const int tr = tid >> 4, tc = tid & 15;
    float acc[8][8] = {};

    for (int kt = 0; kt < 4; kt++) {
        const int kbase = kt * 32;
        {
            const float4* src = (const float4*)(W + kbase * 128);
            float4* dst = (float4*)Ws;
            for (int i = tid; i < 1024; i += 256) dst[i] = src[i];
        }
        {
            int r  = tid >> 1;
            int rr = row0 + r; if (rr >= N_NODES) rr = N_NODES - 1;
            int k0 = (tid & 1) * 16;
            const float4* src = (const float4*)(X + (size_t)rr * 128 + kbase + k0);
#pragma unroll
            for (int i = 0; i < 4; i++) {
                float4 v = src[i];
                int k = k0 + i * 4;
                XT[(k + 0) * 128 + r] = v.x;
                XT[(k + 1) * 128 + r] = v.y;
                XT[(k + 2) * 128 + r] = v.z;
                XT[(k + 3) * 128 + r] = v.w;
            }
        }
        __syncthreads();
#pragma unroll 4
        for (int k = 0; k < 32; k++) {
            float xs[8], ws[8];
            *(float4*)&xs[0] = *(const float4*)(XT + k * 128 + tr * 8);
            *(float4*)&xs[4] = *(const float4*)(XT + k * 128 + tr * 8 + 4);
            *(float4*)&ws[0] = *(const float4*)(Ws + k * 128 + tc * 8);
            *(float4*)&ws[4] = *(const float4*)(Ws + k * 128 + tc * 8 + 4);
#pragma unroll
            for (int i = 0; i < 8; i++)
#pragma unroll
                for (int j = 0; j < 8; j++)
                    acc[i][j] += xs[i] * ws[j];
        }
        __syncthreads();
    }
#pragma unroll
    for (int i = 0; i < 8; i++) {
        int r = row0 + tr * 8 + i;
        if (r < N_NODES) {
            uint4 p;
            p.x = f2h(acc[i][0], acc[i][1]);
            p.y = f2h(acc[i][2], acc[i][3]);
            p.z = f2h(acc[i][4], acc[i][5]);
            p.w = f2h(acc[i][6], acc[i][7]);
            *(uint4*)(Yh + (size_t)r * 128 + tc * 8) = p;
        }
    }
}

// ---------------------------------------------------------------------------
// Layer-1 agg + row-local gemm2 fusion. 512 threads = 8 waves; 16 nodes/block
// with 2 serial nodes per wave (halved serial chain vs r15). cnt/dinv read
// directly from packed (no dinv/cnt arrays, no unpack kernel).
// h1 staged in LDS (16x136 fp16); MFMA phase: wave wv -> col-tile wv.
// ---------------------------------------------------------------------------
__global__ __launch_bounds__(512) void agg1_gemm2_kernel(const __half* __restrict__ xw1,
                                                         const unsigned long long* __restrict__ packed,
                                                         const unsigned int* __restrict__ bucket,
                                                         const float* __restrict__ b1,
                                                         const float* __restrict__ W2,
                                                         __half* __restrict__ x2) {
    __shared__ _Float16 sh1[16][136];
    const int wv   = threadIdx.x >> 6;     // 0..7
    const int lane = threadIdx.x & 63;
    const unsigned int* xh = (const unsigned int*)xw1;
    const int node0 = blockIdx.x * 16;

    float2 bb = ((const float2*)b1)[lane];

#pragma unroll
    for (int j = 0; j < 2; j++) {
        int node = node0 + wv * 2 + j;
        int n; float dv;
        unpack_pd(packed[node], n, dv);

        unsigned pk = 0u;
        if (lane < n) {
            unsigned eh = bucket[(size_t)node * CAP + lane];
            int src = eh & 0xFFFFu;
            int sn; float sdv;
            unpack_pd(packed[src], sn, sdv);
            float v = hu2f((unsigned short)(eh >> 16)) * sdv;
            pk = (unsigned)src | ((unsigned)__half_as_ushort(__float2half_rn(v)) << 16);
        }
        int pki = (int)pk;

        float2 xs = h2f(xh[(size_t)node * 64 + lane]);
        float accx = dv * xs.x;
        float accy = dv * xs.y;

        int i = 0;
        for (; i + 3 < n; i += 4) {
            unsigned v0u = (unsigned)__shfl(pki, i);
            unsigned v1u = (unsigned)__shfl(pki, i + 1);
            unsigned v2u = (unsigned)__shfl(pki, i + 2);
            unsigned v3u = (unsigned)__shfl(pki, i + 3);
            int r0 = v0u & 0xFFFF, r1 = v1u & 0xFFFF, r2 = v2u & 0xFFFF, r3 = v3u & 0xFFFF;
            float v0 = hu2f((unsigned short)(v0u >> 16));
            float v1 = hu2f((unsigned short)(v1u >> 16));
            float v2 = hu2f((unsigned short)(v2u >> 16));
            float v3 = hu2f((unsigned short)(v3u >> 16));
            float2 f0 = h2f(xh[(size_t)r0 * 64 + lane]);
            float2 f1 = h2f(xh[(size_t)r1 * 64 + lane]);
            float2 f2 = h2f(xh[(size_t)r2 * 64 + lane]);
            float2 f3 = h2f(xh[(size_t)r3 * 64 + lane]);
            accx += v0 * f0.x + v1 * f1.x + v2 * f2.x + v3 * f3.x;
            accy += v0 * f0.y + v1 * f1.y + v2 * f2.y + v3 * f3.y;
        }
        for (; i < n; i++) {
            unsigned v0u = (unsigned)__shfl(pki, i);
            int r0 = v0u & 0xFFFF;
            float v0 = hu2f((unsigned short)(v0u >> 16));
            float2 f0 = h2f(xh[(size_t)r0 * 64 + lane]);
            accx += v0 * f0.x;
            accy += v0 * f0.y;
        }

        float hx = fmaxf(dv * accx + bb.x, 0.0f);
        float hy = fmaxf(dv * accy + bb.y, 0.0f);
        int lr = wv * 2 + j;
        sh1[lr][lane * 2]     = (_Float16)hx;
        sh1[lr][lane * 2 + 1] = (_Float16)hy;
    }
    __syncthreads();

    // --- MFMA: rows node0..node0+15; wave wv computes col-tile wv (16 cols).
    const int quad = lane >> 4;
    const int l16  = lane & 15;
    float4v acc0 = {};
#pragma unroll
    for (int kc = 0; kc < 4; kc++) {
        const int k0 = kc * 32;
        half8 a = *(const half8*)(&sh1[l16][k0 + quad * 8]);
        const float* wp = W2 + (size_t)(k0 + quad * 8) * 128 + wv * 16 + l16;
        half8 b;
#pragma unroll
        for (int jj = 0; jj < 8; jj++) b[jj] = (_Float16)wp[jj * 128];
        acc0 = __builtin_amdgcn_mfma_f32_16x16x32_f16(a, b, acc0, 0, 0, 0);
    }
#pragma unroll
    for (int r = 0; r < 4; r++) {
        int row = node0 + quad * 4 + r;
        int rn; float s;
        unpack_pd(packed[row], rn, s);
        x2[(size_t)row * 128 + wv * 16 + l16] = __float2half_rn(acc0[r] * s);
    }
}

// ---------------------------------------------------------------------------
// Layer-2 aggregation FUSED with head dot: nodedot[c] = relu(h2[c]) . Wh
// x2' carries dinv factors; bucket vals are raw ew. Plain store, no fences.
// ---------------------------------------------------------------------------
__global__ __launch_bounds__(256) void agg_head_kernel(const __half* __restrict__ xwh,
                                                       const unsigned long long* __restrict__ packed,
                                                       const unsigned int* __restrict__ bucket,
                                                       const float* __restrict__ bias,
                                                       const float* __restrict__ Wh,
                                                       float* __restrict__ nodedot) {
    int node = blockIdx.x * 4 + (threadIdx.x >> 6);
    int lane = threadIdx.x & 63;
    const unsigned int* xh = (const unsigned int*)xwh;

    int n; float dv;
    unpack_pd(packed[node], n, dv);

    unsigned int ehdr = (lane < n) ? bucket[(size_t)node * CAP + lane] : 0u;
    int eh = (int)ehdr;

    float2 xs = h2f(xh[(size_t)node * 64 + lane]);
    float accx = xs.x;
    float accy = xs.y;

    int i = 0;
    for (; i + 3 < n; i += 4) {
        unsigned v0u = (unsigned)__shfl(eh, i);
        unsigned v1u = (unsigned)__shfl(eh, i + 1);
        unsigned v2u = (unsigned)__shfl(eh, i + 2);
        unsigned v3u = (unsigned)__shfl(eh, i + 3);
        int r0 = v0u & 0xFFFF, r1 = v1u & 0xFFFF, r2 = v2u & 0xFFFF, r3 = v3u & 0xFFFF;
        float v0 = hu2f((unsigned short)(v0u >> 16));
        float v1 = hu2f((unsigned short)(v1u >> 16));
        float v2 = hu2f((unsigned short)(v2u >> 16));
        float v3 = hu2f((unsigned short)(v3u >> 16));
        float2 f0 = h2f(xh[(size_t)r0 * 64 + lane]);
        float2 f1 = h2f(xh[(size_t)r1 * 64 + lane]);
        float2 f2 = h2f(xh[(size_t)r2 * 64 + lane]);
        float2 f3 = h2f(xh[(size_t)r3 * 64 + lane]);
        accx += v0 * f0.x + v1 * f1.x + v2 * f2.x + v3 * f3.x;
        accy += v0 * f0.y + v1 * f1.y + v2 * f2.y + v3 * f3.y;
    }
    for (; i < n; i++) {
        unsigned v0u = (unsigned)__shfl(eh, i);
        int r0 = v0u & 0xFFFF;
        float v0 = hu2f((unsigned short)(v0u >> 16));
        float2 f0 = h2f(xh[(size_t)r0 * 64 + lane]);
        accx += v0 * f0.x;
        accy += v0 * f0.y;
    }

    float2 b = ((const float2*)bias)[lane];
    float hx = fmaxf(dv * accx + b.x, 0.0f);
    float hy = fmaxf(dv * accy + b.y, 0.0f);
    float2 w = ((const float2*)Wh)[lane];
    float s = hx * w.x + hy * w.y;
#pragma unroll
    for (int off = 32; off > 0; off >>= 1) s += __shfl_down(s, off, 64);
    if (lane == 0) nodedot[node] = s;
}

// ---------------------------------------------------------------------------
// out[g] = (sum nodedot over graph)/cnt + bh; graph bounds via binary search
// in sorted batch (gstart array and its producer kernel eliminated).
// ---------------------------------------------------------------------------
__global__ __launch_bounds__(256) void final2_kernel(const float* __restrict__ nodedot,
                                                     const int* __restrict__ batch,
                                                     const float* __restrict__ bh,
                                                     float* __restrict__ out) {
    __shared__ float red[256];
    int g = blockIdx.x;
    // lower_bound(batch, g) and lower_bound(batch, g+1) — uniform across block
    int lo = 0, hi = N_NODES;
    while (lo < hi) { int mid = (lo + hi) >> 1; if (batch[mid] < g) lo = mid + 1; else hi = mid; }
    int a = lo;
    hi = N_NODES;
    while (lo < hi) { int mid = (lo + hi) >> 1; if (batch[mid] < g + 1) lo = mid + 1; else hi = mid; }
    int b = lo;

    float s = 0.0f;
    for (int n = a + threadIdx.x; n < b; n += 256) s += nodedot[n];
    red[threadIdx.x] = s;
    __syncthreads();
#pragma unroll
    for (int off = 128; off > 0; off >>= 1) {
        if (threadIdx.x < off) red[threadIdx.x] += red[threadIdx.x + off];
        __syncthreads();
    }
    if (threadIdx.x == 0)
        out[g] = red[0] / fmaxf((float)(b - a), 1.0f) + bh[0];
}

// ---------------------------------------------------------------------------
extern "C" void kernel_launch(void* const* d_in, const int* in_sizes, int n_in,
                              void* d_out, int out_size, void* d_ws, size_t ws_size,
                              hipStream_t stream) {
    const float* x   = (const float*)d_in[0];
    const float* ew  = (const float*)d_in[1];
    const float* W1  = (const float*)d_in[2];
    const float* b1  = (const float*)d_in[3];
    const float* W2  = (const float*)d_in[4];
    const float* b2  = (const float*)d_in[5];
    const float* Wh  = (const float*)d_in[6];
    const float* bh  = (const float*)d_in[7];
    const int*   ei  = (const int*)d_in[8];
    const int*   bat = (const int*)d_in[9];
    float* out = (float*)d_out;

    char* ws = (char*)d_ws;
    __half* bufAh  = (__half*)ws;                         ws += (size_t)N_NODES * D * 2;
    __half* bufBh  = (__half*)ws;                         ws += (size_t)N_NODES * D * 2;
    unsigned int* bucket = (unsigned int*)ws;             ws += (size_t)N_NODES * CAP * 4;
    unsigned long long* packed = (unsigned long long*)ws; ws += (size_t)N_NODES * 8;
    float*  nodedot = (float*)ws;                         ws += (size_t)N_NODES * 4;

    const int nb_agg4 = N_NODES / 4;                  // 12500

    hipMemsetAsync(packed, 0, (size_t)N_NODES * 8, stream);

    // gemm1 (x@W1 -> fp16, unscaled) overlapped with fill (atomic-floor-bound)
    fused_gemm1_fill<<<NB_GEMM1 + NB_FILL, 256, 0, stream>>>(x, W1, bufAh, ei, ew, packed, bucket);

    // layer 1 agg + row-local gemm2 fusion -> x2' in bufBh (packed-direct)
    agg1_gemm2_kernel<<<NB_AGG16, 512, 0, stream>>>(bufAh, packed, bucket, b1, W2, bufBh);

    // layer 2 agg + head dot (packed-direct)
    agg_head_kernel<<<nb_agg4, 256, 0, stream>>>(bufBh, packed, bucket, b2, Wh, nodedot);

    // segment-sum + head bias (binary-search bounds)
    final2_kernel<<<N_GRAPHS, 256, 0, stream>>>(nodedot, bat, bh, out);
}